// Round 16
// baseline (1644.839 us; speedup 1.0000x reference)
//
#include <hip/hip_runtime.h>
#include <hip/hip_bf16.h>
#include <hip/hip_cooperative_groups.h>
#include <math.h>

// Sizes
#define BB 256
#define SS 64
#define EE 300
#define EPX 320   // X padded
#define KP 832    // 320 + 512
#define VV 30000
#define HH 512
#define H2 1024
#define DA 350
#define RR 8
#define CC 150
#define PP 16
#define CP 2400
#define NFLAG (SS * 2 * 4)

// Output layout (elements, fp32)
#define ATT_OFF    0L
#define CL_OFF     131072L
#define PRED_OFF   169472L
#define ROUTES_OFF 5084672L

typedef _Float16 f16;
typedef f16  f16x8 __attribute__((ext_vector_type(8)));
typedef f16  f16x4 __attribute__((ext_vector_type(4)));
typedef float f32x4 __attribute__((ext_vector_type(4)));

static __device__ __forceinline__ float sigmH(float x) { return 1.0f / (1.0f + expf(-x)); }

// ---------------------------------------------------------------------------
// Fused staging: X16 gather | W16 pack | ws1_16 pack | flag zero, one kernel.
// ---------------------------------------------------------------------------
#define NG_ ((long)SS * BB * EPX)        // 5,242,880
#define NW_ ((long)2 * 2048 * KP)        // 3,407,872
#define NS_ ((long)384 * 1024)           //   393,216
__global__ __launch_bounds__(256) void h_stage(
    const int* __restrict__ ids, const float* __restrict__ emb,
    const float* __restrict__ wihF, const float* __restrict__ whhF,
    const float* __restrict__ wihB, const float* __restrict__ whhB,
    const float* __restrict__ ws1,
    f16* __restrict__ X16, f16* __restrict__ W16, f16* __restrict__ ws1_16,
    unsigned* __restrict__ flags)
{
    const long idx = (long)blockIdx.x * 256 + threadIdx.x;
    if (idx < NG_) {
        const int e = (int)(idx % EPX);
        const int row = (int)(idx / EPX);
        const int s = row >> 8, b = row & 255;
        int tok = ids[(long)b * SS + s];
        if ((unsigned)tok >= (unsigned)VV) tok = 0;
        X16[idx] = (e < EE) ? (f16)emb[(long)tok * EE + e] : (f16)0.0f;
    } else if (idx < NG_ + NW_) {
        const long i2 = idx - NG_;
        const int dir = (int)(i2 / (2048 * KP));
        const int rem = (int)(i2 % (2048 * KP));
        const int j = rem / KP, k = rem % KP;
        const float* wih = dir ? wihB : wihF;
        const float* whh = dir ? whhB : whhF;
        float v;
        if (k < EE)        v = wih[(long)j * EE + k];
        else if (k < EPX)  v = 0.0f;
        else               v = whh[(long)j * HH + (k - EPX)];
        W16[i2] = (f16)v;
    } else if (idx < NG_ + NW_ + NS_) {
        const long i3 = idx - NG_ - NW_;
        const int j = (int)(i3 >> 10);
        ws1_16[i3] = (j < DA) ? (f16)ws1[i3] : (f16)0.0f;
    } else if (idx < NG_ + NW_ + NS_ + NFLAG) {
        flags[idx - NG_ - NW_ - NS_] = 0u;
    }
}

// capsT16[r][2432][1024] transposed; rows >= 2400 zero. LDS 32x32 tiles.
__global__ __launch_bounds__(256) void h_packcapsT(
    const float* __restrict__ caps, f16* __restrict__ capsT)
{
    __shared__ float t[32][33];
    const int r = blockIdx.z, k0 = blockIdx.x * 32, n0 = blockIdx.y * 32;
    const int tx = threadIdx.x & 31, ty = threadIdx.x >> 5;
    #pragma unroll
    for (int p = 0; p < 4; ++p) {
        const int k = k0 + ty + p * 8;
        const int n = n0 + tx;
        t[ty + p * 8][tx] = (n < CP) ? caps[((long)r * H2 + k) * CP + n] : 0.0f;
    }
    __syncthreads();
    #pragma unroll
    for (int p = 0; p < 4; ++p) {
        const int n = n0 + ty + p * 8;
        if (n < 2432)
            capsT[((long)r * 2432 + n) * H2 + k0 + tx] = (f16)t[tx][ty + p * 8];
    }
}

// ---------------------------------------------------------------------------
// Persistent LSTM v4: minimal sync path.
// 256 blocks x 512 thr; dir = bid&1, bq = (bid>>1)&3, ut = bid>>3 (group =
// bid&7 -> XCD-local). Waves: bt = wave&3, kh = wave>>2.
// Per step: [per-wave spin] -> h-MFMAs -> kh1 part write -> ONE barrier ->
// kh0: part reduce + epilogue + hstage (intra-wave) + hx u64 store +
// vmcnt(0) + per-wave flag (threshold 128) -> hs16 archive (off-path) ->
// x-prefetch(s+1). Race-freedom: flag(s)>=128 implies all blocks passed
// mid-barrier(s), so hx parity reuse at s+1 is safe.
// ---------------------------------------------------------------------------
__global__ __launch_bounds__(512, 1) void p_lstm4(
    const f16* __restrict__ X16, f16* __restrict__ hs16,
    f16* __restrict__ hx, unsigned* __restrict__ flags,
    const f16* __restrict__ W16,
    const float* __restrict__ bihF, const float* __restrict__ bhhF,
    const float* __restrict__ bihB, const float* __restrict__ bhhB)
{
    __shared__ f16 Wl[4 * 26 * 64 * 8];   // 104 KB, fragment-ordered
    __shared__ f32x4 part[4][64][4];      // 16 KB
    __shared__ f16 hstage[4][16][16];     // 2 KB, per-bt (per-wave) slices

    const int bid = blockIdx.x;
    const int dir = bid & 1;
    const int bq  = (bid >> 1) & 3;
    const int ut  = bid >> 3;
    const int u0  = ut * 16;
    const int b0  = bq * 64;
    const int tid = threadIdx.x;
    const int wave = tid >> 6, lane = tid & 63;
    const int bt = wave & 3, kh = wave >> 2;
    const int l15 = lane & 15;
    const int kgrp = (lane >> 4) * 8;

    // One-time weight gather into fragment order
    {
        const f16* Wsrc = W16 + (long)dir * 2048 * KP;
        for (int f = tid; f < 4 * 26 * 64; f += 512) {
            const int g  = f / (26 * 64);
            const int rm = f % (26 * 64);
            const int kt = rm >> 6, ln = rm & 63;
            const long src = ((long)g * HH + u0 + (ln & 15)) * KP + kt * 32 + ((ln >> 4) * 8);
            *(f16x8*)(Wl + (long)f * 8) = *(const f16x8*)(Wsrc + src);
        }
    }
    __syncthreads();

    const int arow = b0 + bt * 16 + l15;
    const int u = u0 + l15;
    const float* bi = dir ? bihB : bihF;
    const float* bh = dir ? bhhB : bhhF;
    const float bias0 = bi[u]          + bh[u];
    const float bias1 = bi[HH + u]     + bh[HH + u];
    const float bias2 = bi[2 * HH + u] + bh[2 * HH + u];
    const float bias3 = bi[3 * HH + u] + bh[3 * HH + u];
    const int rbase = (lane >> 4) * 4;
    float cc[4] = {0.f, 0.f, 0.f, 0.f};

    f32x4 xacc[4];
    const int xb = kh ? 5 : 0;
    auto computeX = [&](int se) {
        #pragma unroll
        for (int g = 0; g < 4; ++g) xacc[g] = (f32x4){0.f, 0.f, 0.f, 0.f};
        const f16* Xrow = X16 + ((long)se * BB + arow) * EPX;
        #pragma unroll
        for (int j = 0; j < 5; ++j) {
            const int kt = xb + j;
            const int k0 = kt * 32 + kgrp;
            const f16x8 afr = *(const f16x8*)(Xrow + k0);
            #pragma unroll
            for (int g = 0; g < 4; ++g) {
                const f16x8 bfr = *(const f16x8*)(Wl + (((g * 26 + kt) << 6) + lane) * 8);
                xacc[g] = __builtin_amdgcn_mfma_f32_16x16x32_f16(afr, bfr, xacc[g], 0, 0, 0);
            }
        }
    };
    computeX(dir ? (SS - 1) : 0);

    const int hb = kh ? 8 : 0;
    for (int s = 0; s < SS; ++s) {
        const int s_eff = dir ? (SS - 1 - s) : s;

        // per-wave spin: whole wave blocks while lane0 polls (exec-mask)
        if (s > 0) {
            if (lane == 0) {
                const int fi = ((s - 1) * 2 + dir) * 4 + bq;
                int guard = 0;
                while (__hip_atomic_load(&flags[fi], __ATOMIC_RELAXED,
                                         __HIP_MEMORY_SCOPE_AGENT) < 128u) {
                    __builtin_amdgcn_s_sleep(2);
                    if (++guard > (1 << 22)) break;   // fail loud, not hung
                }
            }
            asm volatile("" ::: "memory");
        }

        f32x4 acc[4];
        #pragma unroll
        for (int g = 0; g < 4; ++g) acc[g] = xacc[g];

        if (s > 0) {
            const f16* hrow = hx + ((((long)((s - 1) & 1) * 2 + dir) * BB) + arow) * HH;
            #pragma unroll
            for (int j = 0; j < 8; ++j) {
                const int kt = 10 + hb + j;
                const int hk = (hb + j) * 32 + kgrp;
                union { unsigned long long q[2]; f16x8 v; } uu;
                const unsigned long long* hp = (const unsigned long long*)(hrow + hk);
                uu.q[0] = __hip_atomic_load(hp,     __ATOMIC_RELAXED, __HIP_MEMORY_SCOPE_AGENT);
                uu.q[1] = __hip_atomic_load(hp + 1, __ATOMIC_RELAXED, __HIP_MEMORY_SCOPE_AGENT);
                #pragma unroll
                for (int g = 0; g < 4; ++g) {
                    const f16x8 bfr = *(const f16x8*)(Wl + (((g * 26 + kt) << 6) + lane) * 8);
                    acc[g] = __builtin_amdgcn_mfma_f32_16x16x32_f16(uu.v, bfr, acc[g], 0, 0, 0);
                }
            }
        }

        if (kh == 1) {
            #pragma unroll
            for (int g = 0; g < 4; ++g) part[bt][lane][g] = acc[g];
        }
        __syncthreads();   // the ONE block barrier per step

        if (kh == 0) {
            #pragma unroll
            for (int g = 0; g < 4; ++g) acc[g] += part[bt][lane][g];
            #pragma unroll
            for (int i = 0; i < 4; ++i) {
                const float zi = acc[0][i] + bias0;
                const float zf = acc[1][i] + bias1;
                const float zg = acc[2][i] + bias2;
                const float zo = acc[3][i] + bias3;
                cc[i] = sigmH(zf) * cc[i] + sigmH(zi) * tanhf(zg);
                hstage[bt][rbase + i][l15] = (f16)(sigmH(zo) * tanhf(cc[i]));
            }
            asm volatile("s_waitcnt lgkmcnt(0)" ::: "memory");
            __builtin_amdgcn_sched_barrier(0);

            // intra-wave transpose readback: lane -> (row, 4-unit chunk)
            const int row = lane >> 2, ch = lane & 3;
            union { unsigned long long q; f16 h4[4]; } pk;
            pk.h4[0] = hstage[bt][row][ch * 4 + 0];
            pk.h4[1] = hstage[bt][row][ch * 4 + 1];
            pk.h4[2] = hstage[bt][row][ch * 4 + 2];
            pk.h4[3] = hstage[bt][row][ch * 4 + 3];
            const int brow = b0 + bt * 16 + row;
            __hip_atomic_store(
                (unsigned long long*)(hx + (((long)(s & 1) * 2 + dir) * BB
                                            + brow) * HH + u0 + ch * 4),
                pk.q, __ATOMIC_RELAXED, __HIP_MEMORY_SCOPE_AGENT);
            asm volatile("s_waitcnt vmcnt(0)" ::: "memory");
            if (lane == 0)
                __hip_atomic_fetch_add(&flags[(s * 2 + dir) * 4 + bq], 1u,
                                       __ATOMIC_RELAXED, __HIP_MEMORY_SCOPE_AGENT);

            // hs16 archive: off the critical path (after flag post)
            *(unsigned long long*)(hs16 + ((long)brow * SS + s_eff) * H2
                                   + dir * HH + u0 + ch * 4) = pk.q;
        }

        if (s + 1 < SS) computeX(dir ? (SS - 2 - s) : (s + 1));
    }
}

// ---------------------------------------------------------------------------
// pre GEMM: block = 64 m-rows x 192 n (nt=12), grid (2, 256).
// ---------------------------------------------------------------------------
__global__ __launch_bounds__(256) void h_preG(
    const f16* __restrict__ hs16, const f16* __restrict__ ws1_16,
    f16* __restrict__ pre16)
{
    const int n0 = blockIdx.x * 192;
    const int m0 = blockIdx.y * 64;
    const int tid = threadIdx.x;
    const int wave = tid >> 6, lane = tid & 63;
    const int l15 = lane & 15;
    const int kgrp = (lane >> 4) * 8;
    const f16* Arow = hs16 + (long)(m0 + wave * 16 + l15) * H2;

    f32x4 acc[12];
    #pragma unroll
    for (int nt = 0; nt < 12; ++nt) acc[nt] = (f32x4){0.f, 0.f, 0.f, 0.f};

    for (int kt = 0; kt < 32; ++kt) {
        const int k0 = kt * 32 + kgrp;
        const f16x8 afr = *(const f16x8*)(Arow + k0);
        #pragma unroll
        for (int nt = 0; nt < 12; ++nt) {
            const f16x8 bfr = *(const f16x8*)(ws1_16 + (long)(n0 + nt * 16 + l15) * H2 + k0);
            acc[nt] = __builtin_amdgcn_mfma_f32_16x16x32_f16(afr, bfr, acc[nt], 0, 0, 0);
        }
    }

    const int rbase = (lane >> 4) * 4;
    #pragma unroll
    for (int nt = 0; nt < 12; ++nt) {
        const int n = n0 + nt * 16 + l15;
        if (n < DA) {
            #pragma unroll
            for (int i = 0; i < 4; ++i) {
                const int m = m0 + wave * 16 + rbase + i;
                pre16[(long)m * DA + n] = (f16)tanhf(acc[nt][i]);
            }
        }
    }
}

// ---------------------------------------------------------------------------
// Fused attention: logits (dot-350) + softmax, one block per batch b.
// ---------------------------------------------------------------------------
__global__ __launch_bounds__(256) void h_att(
    const f16* __restrict__ pre16, const float* __restrict__ ws2,
    float* __restrict__ att_out)
{
    __shared__ f16 preS[SS * DA];     // 44.8 KB
    __shared__ float w2S[RR * DA];    // 11.2 KB
    __shared__ float logS[RR * SS];   //  2 KB
    __shared__ float rmax[RR], rsum[RR];
    const int b = blockIdx.x, tid = threadIdx.x;
    {
        const unsigned long long* src =
            (const unsigned long long*)(pre16 + (long)b * SS * DA);
        unsigned long long* dst = (unsigned long long*)preS;
        for (int i = tid; i < SS * DA / 4; i += 256) dst[i] = src[i];
    }
    for (int i = tid; i < RR * DA; i += 256) w2S[i] = ws2[i];
    __syncthreads();
    for (int pp = tid; pp < RR * SS; pp += 256) {
        const int r = pp >> 6, s = pp & 63;
        const f16* prow = &preS[s * DA];
        const float* wrow = &w2S[r * DA];
        float a = 0.0f;
        for (int k = 0; k < DA; ++k) a = fmaf((float)prow[k], wrow[k], a);
        logS[r * SS + s] = a;
    }
    __syncthreads();
    if (tid < RR) {
        float mx = -1e30f;
        for (int s = 0; s < SS; ++s) mx = fmaxf(mx, logS[tid * SS + s]);
        float sm = 0.0f;
        for (int s = 0; s < SS; ++s) sm += expf(logS[tid * SS + s] - mx);
        rmax[tid] = mx; rsum[tid] = sm;
    }
    __syncthreads();
    for (int pp = tid; pp < RR * SS; pp += 256) {
        const int r = pp >> 6;
        att_out[(long)b * RR * SS + pp] = expf(logS[pp] - rmax[r]) / rsum[r];
    }
}

// sem16: one block per b; hs16 read once; acc[8][4] in registers.
__global__ __launch_bounds__(256) void h_sem(
    const float* __restrict__ att, const f16* __restrict__ hs16,
    f16* __restrict__ sem16)
{
    __shared__ float aS[RR * SS];
    const int b = blockIdx.x, tid = threadIdx.x;
    for (int i = tid; i < RR * SS; i += 256) aS[i] = att[(long)b * RR * SS + i];
    __syncthreads();
    const int d0 = tid * 4;
    float acc[RR][4] = {};
    const f16* hb = hs16 + (long)b * SS * H2;
    for (int s = 0; s < SS; ++s) {
        const f16x4 hv = *(const f16x4*)(hb + s * H2 + d0);
        const float h0 = hv[0], h1 = hv[1], h2 = hv[2], h3 = hv[3];
        #pragma unroll
        for (int r = 0; r < RR; ++r) {
            const float a = aS[r * SS + s];
            acc[r][0] = fmaf(a, h0, acc[r][0]);
            acc[r][1] = fmaf(a, h1, acc[r][1]);
            acc[r][2] = fmaf(a, h2, acc[r][2]);
            acc[r][3] = fmaf(a, h3, acc[r][3]);
        }
    }
    #pragma unroll
    for (int r = 0; r < RR; ++r) {
        f16x4 o; o[0] = (f16)acc[r][0]; o[1] = (f16)acc[r][1];
        o[2] = (f16)acc[r][2]; o[3] = (f16)acc[r][3];
        *(f16x4*)(sem16 + ((long)b * RR + r) * H2 + d0) = o;
    }
}

// ---------------------------------------------------------------------------
// pred GEMM: block = (64-n tile, r), full M=256. 8 waves x 2 m-tiles.
// ---------------------------------------------------------------------------
__global__ __launch_bounds__(512) void h_predG(
    const f16* __restrict__ sem16, const f16* __restrict__ capsT16,
    float* __restrict__ pred_out)
{
    const int n0 = blockIdx.x * 64;
    const int r  = blockIdx.y;
    const int tid = threadIdx.x;
    const int wave = tid >> 6, lane = tid & 63;
    const int l15 = lane & 15;
    const int kgrp = (lane >> 4) * 8;
    const f16* Bp = capsT16 + (long)r * 2432 * H2;
    const f16* A0 = sem16 + ((long)(wave * 32 + l15) * RR + r) * H2;

    f32x4 acc[2][4];
    #pragma unroll
    for (int mt = 0; mt < 2; ++mt)
        #pragma unroll
        for (int nt = 0; nt < 4; ++nt) acc[mt][nt] = (f32x4){0.f, 0.f, 0.f, 0.f};

    for (int kt = 0; kt < 32; ++kt) {
        const int k0 = kt * 32 + kgrp;
        const f16x8 a0 = *(const f16x8*)(A0 + k0);
        const f16x8 a1 = *(const f16x8*)(A0 + (long)16 * RR * H2 + k0);
        #pragma unroll
        for (int nt = 0; nt < 4; ++nt) {
            const f16x8 bfr = *(const f16x8*)(Bp + (long)(n0 + nt * 16 + l15) * H2 + k0);
            acc[0][nt] = __builtin_amdgcn_mfma_f32_16x16x32_f16(a0, bfr, acc[0][nt], 0, 0, 0);
            acc[1][nt] = __builtin_amdgcn_mfma_f32_16x16x32_f16(a1, bfr, acc[1][nt], 0, 0, 0);
        }
    }

    const int rbase = (lane >> 4) * 4;
    #pragma unroll
    for (int mt = 0; mt < 2; ++mt) {
        #pragma unroll
        for (int nt = 0; nt < 4; ++nt) {
            const int n = n0 + nt * 16 + l15;
            if (n < CP) {
                #pragma unroll
                for (int i = 0; i < 4; ++i) {
                    const int m = wave * 32 + mt * 16 + rbase + i;
                    pred_out[((long)m * RR + r) * CP + n] = acc[mt][nt][i];
                }
            }
        }
    }
}

// ---------------------------------------------------------------------------
// Dynamic routing (reads pred fp32 from d_out)
// ---------------------------------------------------------------------------
__global__ __launch_bounds__(256) void h_route(
    const float* __restrict__ pred,
    float* __restrict__ cls_out, float* __restrict__ routes_out)
{
    __shared__ float predS[RR * CP];
    __shared__ float logitS[RR * CC];
    __shared__ float routeS[RR * CC];
    __shared__ float preactS[CP];
    __shared__ float vS[CP];
    __shared__ float scaleS[CC];
    __shared__ float rmax[RR], rsum[RR];
    const int b = blockIdx.x, tid = threadIdx.x;
    const float* ps = pred + (long)b * RR * CP;
    for (int i = tid; i < RR * CP; i += 256) predS[i] = ps[i];
    for (int i = tid; i < RR * CC; i += 256) logitS[i] = 0.0f;
    __syncthreads();

    for (int it = 0; it < 3; ++it) {
        if (tid < RR) {
            float mx = -1e30f;
            for (int c = 0; c < CC; ++c) mx = fmaxf(mx, logitS[tid * CC + c]);
            float sm = 0.0f;
            for (int c = 0; c < CC; ++c) sm += expf(logitS[tid * CC + c] - mx);
            rmax[tid] = mx; rsum[tid] = sm;
        }
        __syncthreads();
        for (int i = tid; i < RR * CC; i += 256) {
            const int r = i / CC;
            routeS[i] = expf(logitS[i] - rmax[r]) / rsum[r];
        }
        __syncthreads();
        for (int cp = tid; cp < CP; cp += 256) {
            const int c = cp >> 4;
            float a = 0.0f;
            #pragma unroll
            for (int r = 0; r < RR; ++r)
                a = fmaf(routeS[r * CC + c], predS[r * CP + cp], a);
            preactS[cp] = a;
        }
        __syncthreads();
        for (int c = tid; c < CC; c += 256) {
            float n2 = 0.0f;
            #pragma unroll
            for (int p = 0; p < PP; ++p) { const float x = preactS[c * PP + p]; n2 = fmaf(x, x, n2); }
            scaleS[c] = (n2 / (1.0f + n2)) / sqrtf(n2 + 1e-9f);
        }
        __syncthreads();
        for (int cp = tid; cp < CP; cp += 256) vS[cp] = preactS[cp] * scaleS[cp >> 4];
        __syncthreads();
        for (int i = tid; i < RR * CC; i += 256) {
            const int r = i / CC, c = i % CC;
            float a = 0.0f;
            #pragma unroll
            for (int p = 0; p < PP; ++p)
                a = fmaf(predS[r * CP + c * PP + p], vS[c * PP + p], a);
            logitS[i] += a;
        }
        __syncthreads();
    }

    for (int i = tid; i < RR * CC; i += 256)
        routes_out[(long)b * RR * CC + i] = routeS[i];
    for (int c = tid; c < CC; c += 256) {
        float n2 = 0.0f;
        #pragma unroll
        for (int p = 0; p < PP; ++p) { const float x = vS[c * PP + p]; n2 = fmaf(x, x, n2); }
        cls_out[(long)b * CC + c] = sqrtf(n2);
    }
}

// ---------------------------------------------------------------------------
extern "C" void kernel_launch(void* const* d_in, const int* in_sizes, int n_in,
                              void* d_out, int out_size, void* d_ws, size_t ws_size,
                              hipStream_t stream)
{
    (void)in_sizes; (void)n_in; (void)out_size;
    const int*   ids   = (const int*)d_in[0];
    const float* emb   = (const float*)d_in[2];
    const float* wih_f = (const float*)d_in[3];
    const float* whh_f = (const float*)d_in[4];
    const float* bih_f = (const float*)d_in[5];
    const float* bhh_f = (const float*)d_in[6];
    const float* wih_b = (const float*)d_in[7];
    const float* whh_b = (const float*)d_in[8];
    const float* bih_b = (const float*)d_in[9];
    const float* bhh_b = (const float*)d_in[10];
    const float* ws1   = (const float*)d_in[11];
    const float* ws2   = (const float*)d_in[12];
    const float* caps  = (const float*)d_in[13];
    float* out = (float*)d_out;   // fp32 outputs

    // Workspace (word offsets); capsT16 aliases low region after h_sem.
    float* ws = (float*)d_ws;
    f16*  hs16   = (f16*)ws;                          // 8,388,608 w
    f16*  hx     = (f16*)(ws + 8388608);              //   262,144 w
    f16*  X16    = (f16*)(ws + 8650752);              // 2,621,440 w
    f16*  W16    = (f16*)(ws + 11272192);             // 1,703,936 w
    f16*  ws1_16 = (f16*)(ws + 12976128);             //   196,608 w
    f16*  sem16  = (f16*)(ws + 13172736);             // 1,048,576 w
    float* attw  = ws + 14221312;                     //   131,072 w
    unsigned* flags = (unsigned*)(ws + 14352384);     //       512 w
    f16*  pre16  = X16;                               // alias (post-LSTM)
    f16*  capsT16 = (f16*)ws;                         // alias (post-sem)
    const size_t need = (size_t)(14352384 + 512) * 4;
    if (ws_size < need) return;

    // Fused staging (X16 | W16 | ws1_16 | flags)
    {
        const long total = NG_ + NW_ + NS_ + NFLAG;
        h_stage<<<(int)((total + 255) / 256), 256, 0, stream>>>(
            ids, emb, wih_f, whh_f, wih_b, whh_b, ws1, X16, W16, ws1_16, flags);
    }

    // Persistent LSTM (all 64 steps, minimal sync path)
    {
        const f16* a0 = X16; f16* a1 = hs16; f16* a2 = hx; unsigned* a3 = flags;
        const f16* a4 = W16;
        const float* a5 = bih_f; const float* a6 = bhh_f;
        const float* a7 = bih_b; const float* a8 = bhh_b;
        void* kargs[] = {(void*)&a0, (void*)&a1, (void*)&a2, (void*)&a3, (void*)&a4,
                         (void*)&a5, (void*)&a6, (void*)&a7, (void*)&a8};
        hipLaunchCooperativeKernel((void*)p_lstm4, dim3(256), dim3(512),
                                   kargs, 0, stream);
    }

    // pre16 = tanh(hs16 @ ws1^T), f16 out
    h_preG<<<dim3(2, 256), 256, 0, stream>>>(hs16, ws1_16, pre16);

    // fused attention logits + softmax
    h_att<<<BB, 256, 0, stream>>>(pre16, ws2, attw);
    // copy attention to output (fp32): att_out == attw region written directly
    // (h_att wrote into attw; emit to d_out as part of h_sem read path)
    hipMemcpyAsync(out + ATT_OFF, attw, (size_t)BB * RR * SS * 4,
                   hipMemcpyDeviceToDevice, stream);

    h_sem<<<BB, 256, 0, stream>>>(attw, hs16, sem16);

    // caps -> capsT16 (hs16 region dead after h_sem)
    h_packcapsT<<<dim3(32, 76, 8), 256, 0, stream>>>(caps, capsT16);

    // pred = sem16 @ caps, fp32 out
    h_predG<<<dim3(38, 8), 512, 0, stream>>>(sem16, capsT16, out + PRED_OFF);

    h_route<<<BB, 256, 0, stream>>>(out + PRED_OFF, out + CL_OFF, out + ROUTES_OFF);
}

// Round 17
// 834.702 us; speedup vs baseline: 1.9706x; 1.9706x over previous
//
#include <hip/hip_runtime.h>
#include <hip/hip_bf16.h>
#include <hip/hip_cooperative_groups.h>
#include <math.h>

// Sizes
#define BB 256
#define SS 64
#define EE 300
#define EPX 320   // X padded
#define KP 832    // 320 + 512
#define VV 30000
#define HH 512
#define H2 1024
#define DA 350
#define RR 8
#define CC 150
#define PP 16
#define CP 2400
#define NFLAG (SS * 2 * 4)

// Output layout (elements, fp32)
#define ATT_OFF    0L
#define CL_OFF     131072L
#define PRED_OFF   169472L
#define ROUTES_OFF 5084672L

typedef _Float16 f16;
typedef f16  f16x8 __attribute__((ext_vector_type(8)));
typedef f16  f16x4 __attribute__((ext_vector_type(4)));
typedef float f32x4 __attribute__((ext_vector_type(4)));

static __device__ __forceinline__ float sigmJ(float x) { return 1.0f / (1.0f + expf(-x)); }

// ---------------------------------------------------------------------------
// Fused staging: X16 gather | W16 pack | ws1_16 pack | flag zero, one kernel.
// ---------------------------------------------------------------------------
#define NG_ ((long)SS * BB * EPX)        // 5,242,880
#define NW_ ((long)2 * 2048 * KP)        // 3,407,872
#define NS_ ((long)384 * 1024)           //   393,216
__global__ __launch_bounds__(256) void j_stage(
    const int* __restrict__ ids, const float* __restrict__ emb,
    const float* __restrict__ wihF, const float* __restrict__ whhF,
    const float* __restrict__ wihB, const float* __restrict__ whhB,
    const float* __restrict__ ws1,
    f16* __restrict__ X16, f16* __restrict__ W16, f16* __restrict__ ws1_16,
    unsigned* __restrict__ flags)
{
    const long idx = (long)blockIdx.x * 256 + threadIdx.x;
    if (idx < NG_) {
        const int e = (int)(idx % EPX);
        const int row = (int)(idx / EPX);
        const int s = row >> 8, b = row & 255;
        int tok = ids[(long)b * SS + s];
        if ((unsigned)tok >= (unsigned)VV) tok = 0;
        X16[idx] = (e < EE) ? (f16)emb[(long)tok * EE + e] : (f16)0.0f;
    } else if (idx < NG_ + NW_) {
        const long i2 = idx - NG_;
        const int dir = (int)(i2 / (2048 * KP));
        const int rem = (int)(i2 % (2048 * KP));
        const int j = rem / KP, k = rem % KP;
        const float* wih = dir ? wihB : wihF;
        const float* whh = dir ? whhB : whhF;
        float v;
        if (k < EE)        v = wih[(long)j * EE + k];
        else if (k < EPX)  v = 0.0f;
        else               v = whh[(long)j * HH + (k - EPX)];
        W16[i2] = (f16)v;
    } else if (idx < NG_ + NW_ + NS_) {
        const long i3 = idx - NG_ - NW_;
        const int j = (int)(i3 >> 10);
        ws1_16[i3] = (j < DA) ? (f16)ws1[i3] : (f16)0.0f;
    } else if (idx < NG_ + NW_ + NS_ + NFLAG) {
        flags[idx - NG_ - NW_ - NS_] = 0u;
    }
}

// capsT16[r][2432][1024] transposed; rows >= 2400 zero. LDS 32x32 tiles.
__global__ __launch_bounds__(256) void j_packcapsT(
    const float* __restrict__ caps, f16* __restrict__ capsT)
{
    __shared__ float t[32][33];
    const int r = blockIdx.z, k0 = blockIdx.x * 32, n0 = blockIdx.y * 32;
    const int tx = threadIdx.x & 31, ty = threadIdx.x >> 5;
    #pragma unroll
    for (int p = 0; p < 4; ++p) {
        const int k = k0 + ty + p * 8;
        const int n = n0 + tx;
        t[ty + p * 8][tx] = (n < CP) ? caps[((long)r * H2 + k) * CP + n] : 0.0f;
    }
    __syncthreads();
    #pragma unroll
    for (int p = 0; p < 4; ++p) {
        const int n = n0 + ty + p * 8;
        if (n < 2432)
            capsT[((long)r * 2432 + n) * H2 + k0 + tx] = (f16)t[tx][ty + p * 8];
    }
}

// ---------------------------------------------------------------------------
// Persistent LSTM (round-15 v3 protocol, verbatim): 256 blocks x 512 thr.
// dir = bid&1, bq = (bid>>1)&3, ut = bid>>3 -> sync group = bid&7 is
// XCD-local under round-robin dispatch. Waves: bt = wave&3, kh = wave>>2.
// Per step: tid0-spin on group flag -> block barrier -> h-MFMAs (8 kt per
// kh-half) -> partials via LDS -> epilogue -> coalesced hx store + vmcnt(0)
// -> barrier -> tid0 posts flag (threshold 32) -> x-prefetch for s+1.
// ONE poller per block is the design invariant (round-16 lesson: per-wave
// polling = 256 spinners/flag = 2.6x regression from atomic contention).
// ---------------------------------------------------------------------------
__global__ __launch_bounds__(512, 1) void p_lstm5(
    const f16* __restrict__ X16, f16* __restrict__ hs16,
    f16* __restrict__ hx, unsigned* __restrict__ flags,
    const f16* __restrict__ W16,
    const float* __restrict__ bihF, const float* __restrict__ bhhF,
    const float* __restrict__ bihB, const float* __restrict__ bhhB)
{
    __shared__ f16 Wl[4 * 26 * 64 * 8];   // 104 KB, fragment-ordered
    __shared__ f32x4 part[4][64][4];      // 16 KB
    __shared__ f16 hstage[64][16];        // 2 KB

    const int bid = blockIdx.x;
    const int dir = bid & 1;
    const int bq  = (bid >> 1) & 3;
    const int ut  = bid >> 3;
    const int u0  = ut * 16;
    const int b0  = bq * 64;
    const int tid = threadIdx.x;
    const int wave = tid >> 6, lane = tid & 63;
    const int bt = wave & 3, kh = wave >> 2;
    const int l15 = lane & 15;
    const int kgrp = (lane >> 4) * 8;

    // One-time weight gather into fragment order
    {
        const f16* Wsrc = W16 + (long)dir * 2048 * KP;
        for (int f = tid; f < 4 * 26 * 64; f += 512) {
            const int g  = f / (26 * 64);
            const int rm = f % (26 * 64);
            const int kt = rm >> 6, ln = rm & 63;
            const long src = ((long)g * HH + u0 + (ln & 15)) * KP + kt * 32 + ((ln >> 4) * 8);
            *(f16x8*)(Wl + (long)f * 8) = *(const f16x8*)(Wsrc + src);
        }
    }
    __syncthreads();

    const int arow = b0 + bt * 16 + l15;
    const int u = u0 + l15;
    const float* bi = dir ? bihB : bihF;
    const float* bh = dir ? bhhB : bhhF;
    const float bias0 = bi[u]          + bh[u];
    const float bias1 = bi[HH + u]     + bh[HH + u];
    const float bias2 = bi[2 * HH + u] + bh[2 * HH + u];
    const float bias3 = bi[3 * HH + u] + bh[3 * HH + u];
    const int rbase = (lane >> 4) * 4;
    float cc[4] = {0.f, 0.f, 0.f, 0.f};

    f32x4 xacc[4];
    const int xb = kh ? 5 : 0;
    auto computeX = [&](int se) {
        #pragma unroll
        for (int g = 0; g < 4; ++g) xacc[g] = (f32x4){0.f, 0.f, 0.f, 0.f};
        const f16* Xrow = X16 + ((long)se * BB + arow) * EPX;
        #pragma unroll
        for (int j = 0; j < 5; ++j) {
            const int kt = xb + j;
            const int k0 = kt * 32 + kgrp;
            const f16x8 afr = *(const f16x8*)(Xrow + k0);
            #pragma unroll
            for (int g = 0; g < 4; ++g) {
                const f16x8 bfr = *(const f16x8*)(Wl + (((g * 26 + kt) << 6) + lane) * 8);
                xacc[g] = __builtin_amdgcn_mfma_f32_16x16x32_f16(afr, bfr, xacc[g], 0, 0, 0);
            }
        }
    };
    computeX(dir ? (SS - 1) : 0);

    const int hb = kh ? 8 : 0;
    for (int s = 0; s < SS; ++s) {
        const int s_eff = dir ? (SS - 1 - s) : s;

        if (s > 0) {
            if (tid == 0) {
                const int fi = ((s - 1) * 2 + dir) * 4 + bq;
                int guard = 0;
                while (__hip_atomic_load(&flags[fi], __ATOMIC_RELAXED,
                                         __HIP_MEMORY_SCOPE_AGENT) < 32u) {
                    __builtin_amdgcn_s_sleep(1);
                    if (++guard > (1 << 22)) break;   // fail loud, not hung
                }
            }
            __syncthreads();
        }

        f32x4 acc[4];
        #pragma unroll
        for (int g = 0; g < 4; ++g) acc[g] = xacc[g];

        if (s > 0) {
            const f16* hrow = hx + ((((long)((s - 1) & 1) * 2 + dir) * BB) + arow) * HH;
            #pragma unroll
            for (int j = 0; j < 8; ++j) {
                const int kt = 10 + hb + j;
                const int hk = (hb + j) * 32 + kgrp;
                union { unsigned long long q[2]; f16x8 v; } uu;
                const unsigned long long* hp = (const unsigned long long*)(hrow + hk);
                uu.q[0] = __hip_atomic_load(hp,     __ATOMIC_RELAXED, __HIP_MEMORY_SCOPE_AGENT);
                uu.q[1] = __hip_atomic_load(hp + 1, __ATOMIC_RELAXED, __HIP_MEMORY_SCOPE_AGENT);
                #pragma unroll
                for (int g = 0; g < 4; ++g) {
                    const f16x8 bfr = *(const f16x8*)(Wl + (((g * 26 + kt) << 6) + lane) * 8);
                    acc[g] = __builtin_amdgcn_mfma_f32_16x16x32_f16(uu.v, bfr, acc[g], 0, 0, 0);
                }
            }
        }

        if (kh == 1) {
            #pragma unroll
            for (int g = 0; g < 4; ++g) part[bt][lane][g] = acc[g];
        }
        __syncthreads();
        if (kh == 0) {
            #pragma unroll
            for (int g = 0; g < 4; ++g) acc[g] += part[bt][lane][g];
            #pragma unroll
            for (int i = 0; i < 4; ++i) {
                const int b = b0 + bt * 16 + rbase + i;
                const float zi = acc[0][i] + bias0;
                const float zf = acc[1][i] + bias1;
                const float zg = acc[2][i] + bias2;
                const float zo = acc[3][i] + bias3;
                cc[i] = sigmJ(zf) * cc[i] + sigmJ(zi) * tanhf(zg);
                const float hv = sigmJ(zo) * tanhf(cc[i]);
                hs16[((long)b * SS + s_eff) * H2 + dir * HH + u] = (f16)hv;
                hstage[bt * 16 + rbase + i][l15] = (f16)hv;
            }
        }
        __syncthreads();

        // cooperative coalesced hx store (64 rows x 16 u = 256 u64 chunks)
        {
            f16* hxw = hx + (((long)(s & 1) * 2 + dir) * BB) * HH;
            if (tid < 256) {
                const int row = tid >> 2, ch = tid & 3;
                union { unsigned long long q; f16 h4[4]; } pk;
                pk.h4[0] = hstage[row][ch * 4 + 0];
                pk.h4[1] = hstage[row][ch * 4 + 1];
                pk.h4[2] = hstage[row][ch * 4 + 2];
                pk.h4[3] = hstage[row][ch * 4 + 3];
                __hip_atomic_store(
                    (unsigned long long*)(hxw + (long)(b0 + row) * HH + u0 + ch * 4),
                    pk.q, __ATOMIC_RELAXED, __HIP_MEMORY_SCOPE_AGENT);
            }
            asm volatile("s_waitcnt vmcnt(0)" ::: "memory");
        }
        __syncthreads();
        if (tid == 0)
            __hip_atomic_fetch_add(&flags[(s * 2 + dir) * 4 + bq], 1u,
                                   __ATOMIC_RELAXED, __HIP_MEMORY_SCOPE_AGENT);

        // prefetch x-part for next step (independent of h; overlaps sync)
        if (s + 1 < SS) computeX(dir ? (SS - 2 - s) : (s + 1));
    }
}

// ---------------------------------------------------------------------------
// pre GEMM: block = 64 m-rows x 192 n (nt=12), grid (2, 256).
// ---------------------------------------------------------------------------
__global__ __launch_bounds__(256) void j_preG(
    const f16* __restrict__ hs16, const f16* __restrict__ ws1_16,
    f16* __restrict__ pre16)
{
    const int n0 = blockIdx.x * 192;
    const int m0 = blockIdx.y * 64;
    const int tid = threadIdx.x;
    const int wave = tid >> 6, lane = tid & 63;
    const int l15 = lane & 15;
    const int kgrp = (lane >> 4) * 8;
    const f16* Arow = hs16 + (long)(m0 + wave * 16 + l15) * H2;

    f32x4 acc[12];
    #pragma unroll
    for (int nt = 0; nt < 12; ++nt) acc[nt] = (f32x4){0.f, 0.f, 0.f, 0.f};

    for (int kt = 0; kt < 32; ++kt) {
        const int k0 = kt * 32 + kgrp;
        const f16x8 afr = *(const f16x8*)(Arow + k0);
        #pragma unroll
        for (int nt = 0; nt < 12; ++nt) {
            const f16x8 bfr = *(const f16x8*)(ws1_16 + (long)(n0 + nt * 16 + l15) * H2 + k0);
            acc[nt] = __builtin_amdgcn_mfma_f32_16x16x32_f16(afr, bfr, acc[nt], 0, 0, 0);
        }
    }

    const int rbase = (lane >> 4) * 4;
    #pragma unroll
    for (int nt = 0; nt < 12; ++nt) {
        const int n = n0 + nt * 16 + l15;
        if (n < DA) {
            #pragma unroll
            for (int i = 0; i < 4; ++i) {
                const int m = m0 + wave * 16 + rbase + i;
                pre16[(long)m * DA + n] = (f16)tanhf(acc[nt][i]);
            }
        }
    }
}

// ---------------------------------------------------------------------------
// Fused attention: logits (dot-350) + softmax, one block per batch b.
// Writes fp32 attention directly to d_out.
// ---------------------------------------------------------------------------
__global__ __launch_bounds__(256) void j_att(
    const f16* __restrict__ pre16, const float* __restrict__ ws2,
    float* __restrict__ att_out)
{
    __shared__ f16 preS[SS * DA];     // 44.8 KB
    __shared__ float w2S[RR * DA];    // 11.2 KB
    __shared__ float logS[RR * SS];   //  2 KB
    __shared__ float rmax[RR], rsum[RR];
    const int b = blockIdx.x, tid = threadIdx.x;
    {
        const unsigned long long* src =
            (const unsigned long long*)(pre16 + (long)b * SS * DA);
        unsigned long long* dst = (unsigned long long*)preS;
        for (int i = tid; i < SS * DA / 4; i += 256) dst[i] = src[i];
    }
    for (int i = tid; i < RR * DA; i += 256) w2S[i] = ws2[i];
    __syncthreads();
    for (int pp = tid; pp < RR * SS; pp += 256) {
        const int r = pp >> 6, s = pp & 63;
        const f16* prow = &preS[s * DA];
        const float* wrow = &w2S[r * DA];
        float a = 0.0f;
        for (int k = 0; k < DA; ++k) a = fmaf((float)prow[k], wrow[k], a);
        logS[r * SS + s] = a;
    }
    __syncthreads();
    if (tid < RR) {
        float mx = -1e30f;
        for (int s = 0; s < SS; ++s) mx = fmaxf(mx, logS[tid * SS + s]);
        float sm = 0.0f;
        for (int s = 0; s < SS; ++s) sm += expf(logS[tid * SS + s] - mx);
        rmax[tid] = mx; rsum[tid] = sm;
    }
    __syncthreads();
    for (int pp = tid; pp < RR * SS; pp += 256) {
        const int r = pp >> 6;
        att_out[(long)b * RR * SS + pp] = expf(logS[pp] - rmax[r]) / rsum[r];
    }
}

// sem16: one block per b; hs16 read once; acc[8][4] in registers.
__global__ __launch_bounds__(256) void j_sem(
    const float* __restrict__ att, const f16* __restrict__ hs16,
    f16* __restrict__ sem16)
{
    __shared__ float aS[RR * SS];
    const int b = blockIdx.x, tid = threadIdx.x;
    for (int i = tid; i < RR * SS; i += 256) aS[i] = att[(long)b * RR * SS + i];
    __syncthreads();
    const int d0 = tid * 4;
    float acc[RR][4] = {};
    const f16* hb = hs16 + (long)b * SS * H2;
    for (int s = 0; s < SS; ++s) {
        const f16x4 hv = *(const f16x4*)(hb + s * H2 + d0);
        const float h0 = hv[0], h1 = hv[1], h2 = hv[2], h3 = hv[3];
        #pragma unroll
        for (int r = 0; r < RR; ++r) {
            const float a = aS[r * SS + s];
            acc[r][0] = fmaf(a, h0, acc[r][0]);
            acc[r][1] = fmaf(a, h1, acc[r][1]);
            acc[r][2] = fmaf(a, h2, acc[r][2]);
            acc[r][3] = fmaf(a, h3, acc[r][3]);
        }
    }
    #pragma unroll
    for (int r = 0; r < RR; ++r) {
        f16x4 o; o[0] = (f16)acc[r][0]; o[1] = (f16)acc[r][1];
        o[2] = (f16)acc[r][2]; o[3] = (f16)acc[r][3];
        *(f16x4*)(sem16 + ((long)b * RR + r) * H2 + d0) = o;
    }
}

// ---------------------------------------------------------------------------
// pred GEMM: block = (64-n tile, r), full M=256. 8 waves x 2 m-tiles.
// ---------------------------------------------------------------------------
__global__ __launch_bounds__(512) void j_predG(
    const f16* __restrict__ sem16, const f16* __restrict__ capsT16,
    float* __restrict__ pred_out)
{
    const int n0 = blockIdx.x * 64;
    const int r  = blockIdx.y;
    const int tid = threadIdx.x;
    const int wave = tid >> 6, lane = tid & 63;
    const int l15 = lane & 15;
    const int kgrp = (lane >> 4) * 8;
    const f16* Bp = capsT16 + (long)r * 2432 * H2;
    const f16* A0 = sem16 + ((long)(wave * 32 + l15) * RR + r) * H2;

    f32x4 acc[2][4];
    #pragma unroll
    for (int mt = 0; mt < 2; ++mt)
        #pragma unroll
        for (int nt = 0; nt < 4; ++nt) acc[mt][nt] = (f32x4){0.f, 0.f, 0.f, 0.f};

    for (int kt = 0; kt < 32; ++kt) {
        const int k0 = kt * 32 + kgrp;
        const f16x8 a0 = *(const f16x8*)(A0 + k0);
        const f16x8 a1 = *(const f16x8*)(A0 + (long)16 * RR * H2 + k0);
        #pragma unroll
        for (int nt = 0; nt < 4; ++nt) {
            const f16x8 bfr = *(const f16x8*)(Bp + (long)(n0 + nt * 16 + l15) * H2 + k0);
            acc[0][nt] = __builtin_amdgcn_mfma_f32_16x16x32_f16(a0, bfr, acc[0][nt], 0, 0, 0);
            acc[1][nt] = __builtin_amdgcn_mfma_f32_16x16x32_f16(a1, bfr, acc[1][nt], 0, 0, 0);
        }
    }

    const int rbase = (lane >> 4) * 4;
    #pragma unroll
    for (int mt = 0; mt < 2; ++mt) {
        #pragma unroll
        for (int nt = 0; nt < 4; ++nt) {
            const int n = n0 + nt * 16 + l15;
            if (n < CP) {
                #pragma unroll
                for (int i = 0; i < 4; ++i) {
                    const int m = wave * 32 + mt * 16 + rbase + i;
                    pred_out[((long)m * RR + r) * CP + n] = acc[mt][nt][i];
                }
            }
        }
    }
}

// ---------------------------------------------------------------------------
// Dynamic routing (reads pred fp32 from d_out)
// ---------------------------------------------------------------------------
__global__ __launch_bounds__(256) void j_route(
    const float* __restrict__ pred,
    float* __restrict__ cls_out, float* __restrict__ routes_out)
{
    __shared__ float predS[RR * CP];
    __shared__ float logitS[RR * CC];
    __shared__ float routeS[RR * CC];
    __shared__ float preactS[CP];
    __shared__ float vS[CP];
    __shared__ float scaleS[CC];
    __shared__ float rmax[RR], rsum[RR];
    const int b = blockIdx.x, tid = threadIdx.x;
    const float* ps = pred + (long)b * RR * CP;
    for (int i = tid; i < RR * CP; i += 256) predS[i] = ps[i];
    for (int i = tid; i < RR * CC; i += 256) logitS[i] = 0.0f;
    __syncthreads();

    for (int it = 0; it < 3; ++it) {
        if (tid < RR) {
            float mx = -1e30f;
            for (int c = 0; c < CC; ++c) mx = fmaxf(mx, logitS[tid * CC + c]);
            float sm = 0.0f;
            for (int c = 0; c < CC; ++c) sm += expf(logitS[tid * CC + c] - mx);
            rmax[tid] = mx; rsum[tid] = sm;
        }
        __syncthreads();
        for (int i = tid; i < RR * CC; i += 256) {
            const int r = i / CC;
            routeS[i] = expf(logitS[i] - rmax[r]) / rsum[r];
        }
        __syncthreads();
        for (int cp = tid; cp < CP; cp += 256) {
            const int c = cp >> 4;
            float a = 0.0f;
            #pragma unroll
            for (int r = 0; r < RR; ++r)
                a = fmaf(routeS[r * CC + c], predS[r * CP + cp], a);
            preactS[cp] = a;
        }
        __syncthreads();
        for (int c = tid; c < CC; c += 256) {
            float n2 = 0.0f;
            #pragma unroll
            for (int p = 0; p < PP; ++p) { const float x = preactS[c * PP + p]; n2 = fmaf(x, x, n2); }
            scaleS[c] = (n2 / (1.0f + n2)) / sqrtf(n2 + 1e-9f);
        }
        __syncthreads();
        for (int cp = tid; cp < CP; cp += 256) vS[cp] = preactS[cp] * scaleS[cp >> 4];
        __syncthreads();
        for (int i = tid; i < RR * CC; i += 256) {
            const int r = i / CC, c = i % CC;
            float a = 0.0f;
            #pragma unroll
            for (int p = 0; p < PP; ++p)
                a = fmaf(predS[r * CP + c * PP + p], vS[c * PP + p], a);
            logitS[i] += a;
        }
        __syncthreads();
    }

    for (int i = tid; i < RR * CC; i += 256)
        routes_out[(long)b * RR * CC + i] = routeS[i];
    for (int c = tid; c < CC; c += 256) {
        float n2 = 0.0f;
        #pragma unroll
        for (int p = 0; p < PP; ++p) { const float x = vS[c * PP + p]; n2 = fmaf(x, x, n2); }
        cls_out[(long)b * CC + c] = sqrtf(n2);
    }
}

// ---------------------------------------------------------------------------
extern "C" void kernel_launch(void* const* d_in, const int* in_sizes, int n_in,
                              void* d_out, int out_size, void* d_ws, size_t ws_size,
                              hipStream_t stream)
{
    (void)in_sizes; (void)n_in; (void)out_size;
    const int*   ids   = (const int*)d_in[0];
    const float* emb   = (const float*)d_in[2];
    const float* wih_f = (const float*)d_in[3];
    const float* whh_f = (const float*)d_in[4];
    const float* bih_f = (const float*)d_in[5];
    const float* bhh_f = (const float*)d_in[6];
    const float* wih_b = (const float*)d_in[7];
    const float* whh_b = (const float*)d_in[8];
    const float* bih_b = (const float*)d_in[9];
    const float* bhh_b = (const float*)d_in[10];
    const float* ws1   = (const float*)d_in[11];
    const float* ws2   = (const float*)d_in[12];
    const float* caps  = (const float*)d_in[13];
    float* out = (float*)d_out;   // fp32 outputs

    // Workspace (word offsets); capsT16 aliases low region after j_sem.
    float* ws = (float*)d_ws;
    f16*  hs16   = (f16*)ws;                          // 8,388,608 w
    f16*  hx     = (f16*)(ws + 8388608);              //   262,144 w
    f16*  X16    = (f16*)(ws + 8650752);              // 2,621,440 w
    f16*  W16    = (f16*)(ws + 11272192);             // 1,703,936 w
    f16*  ws1_16 = (f16*)(ws + 12976128);             //   196,608 w
    f16*  sem16  = (f16*)(ws + 13172736);             // 1,048,576 w
    unsigned* flags = (unsigned*)(ws + 14221312);     //       512 w
    f16*  pre16  = X16;                               // alias (post-LSTM)
    f16*  capsT16 = (f16*)ws;                         // alias (post-sem)
    const size_t need = (size_t)(14221312 + 512) * 4;
    if (ws_size < need) return;

    // Fused staging (X16 | W16 | ws1_16 | flags)
    {
        const long total = NG_ + NW_ + NS_ + NFLAG;
        j_stage<<<(int)((total + 255) / 256), 256, 0, stream>>>(
            ids, emb, wih_f, whh_f, wih_b, whh_b, ws1, X16, W16, ws1_16, flags);
    }

    // Persistent LSTM (round-15 protocol)
    {
        const f16* a0 = X16; f16* a1 = hs16; f16* a2 = hx; unsigned* a3 = flags;
        const f16* a4 = W16;
        const float* a5 = bih_f; const float* a6 = bhh_f;
        const float* a7 = bih_b; const float* a8 = bhh_b;
        void* kargs[] = {(void*)&a0, (void*)&a1, (void*)&a2, (void*)&a3, (void*)&a4,
                         (void*)&a5, (void*)&a6, (void*)&a7, (void*)&a8};
        hipLaunchCooperativeKernel((void*)p_lstm5, dim3(256), dim3(512),
                                   kargs, 0, stream);
    }

    // pre16 = tanh(hs16 @ ws1^T), f16 out
    j_preG<<<dim3(2, 256), 256, 0, stream>>>(hs16, ws1_16, pre16);

    // fused attention logits + softmax -> d_out directly
    j_att<<<BB, 256, 0, stream>>>(pre16, ws2, out + ATT_OFF);

    j_sem<<<BB, 256, 0, stream>>>(out + ATT_OFF, hs16, sem16);

    // caps -> capsT16 (hs16 region dead after j_sem)
    j_packcapsT<<<dim3(32, 76, 8), 256, 0, stream>>>(caps, capsT16);

    // pred = sem16 @ caps, fp32 out
    j_predG<<<dim3(38, 8), 512, 0, stream>>>(sem16, capsT16, out + PRED_OFF);

    j_route<<<BB, 256, 0, stream>>>(out + PRED_OFF, out + CL_OFF, out + ROUTES_OFF);
}